// Round 5
// baseline (1235.509 us; speedup 1.0000x reference)
//
#include <hip/hip_runtime.h>
#include <hip/hip_bf16.h>
#include <stdint.h>

#define BB 64
#define SS 2048
#define TT 128
#define NB 16              // batches per fwd block
#define FWD_BLOCKS (BB / NB)
#define GRP 6              // renorm interval AND em prefetch group (6*10.8 < 88.7 e-folds)
#define ROWP 136           // padded LDS row stride in bf16 elems

typedef __bf16 bf16x8 __attribute__((ext_vector_type(8)));
typedef float  f32x4  __attribute__((ext_vector_type(4)));

// Raw workgroup barrier that does NOT drain vmcnt: LDS ordering only.
// 0xc07f = lgkmcnt(0), vmcnt(max/no-wait), expcnt(max/no-wait) under both
// gfx9-style and CDNA waitcnt encodings. __syncthreads() would emit
// s_waitcnt vmcnt(0) and kill the in-flight em prefetch every step.
__device__ __forceinline__ void wg_barrier_lds() {
    asm volatile("" ::: "memory");
    __builtin_amdgcn_s_waitcnt(0xc07f);
    __builtin_amdgcn_s_barrier();
    asm volatile("" ::: "memory");
}

// ---- bool-layout detection: mask[0,0] is always true (len >= 1024) ----
__device__ __forceinline__ int detect_mode(const void* maskp) {
    uint32_t w0 = ((const uint32_t*)maskp)[0];
    if (w0 == 1u) return 0;
    if (w0 == 0x3F800000u) return 2;
    if (w0 == 0x3F803F80u) return 3;
    return 1;
}
__device__ __forceinline__ int mask_at(const void* maskp, int mode, size_t idx) {
    if (mode == 0) return ((const int*)maskp)[idx] != 0;
    if (mode == 1) return ((const unsigned char*)maskp)[idx] != 0;
    if (mode == 2) return ((const float*)maskp)[idx] != 0.f;
    return ((const unsigned short*)maskp)[idx] != 0;
}

// ---- MFMA-batched forward scan + posterior, 16 batches per block ----
__global__ __launch_bounds__(256, 1) void fwd_kernel(
    const float* __restrict__ em, const void* __restrict__ maskp,
    const int* __restrict__ tags, const void* __restrict__ forb,
    const float* __restrict__ trans,
    const float* __restrict__ startt, const float* __restrict__ endt,
    double* __restrict__ zout, double* __restrict__ postout)
{
    const int t = threadIdx.x;
    const int w = t >> 6;          // wave 0..3 (owns t_out rows 32w..32w+31)
    const int lane = t & 63;
    const int q = lane >> 4;       // quad 0..3
    const int c = lane & 15;       // batch-within-block (= MFMA n and m index)
    const int blk = blockIdx.x;

    __shared__ __bf16 uS[2 * NB * ROWP];       // double-buffered U (bf16), padded rows
    __shared__ __align__(16) float wred[NB][4];
    __shared__ int   lenS[NB];
    __shared__ float MinitS[NB];

    const int mode = detect_mode(maskp);

    // ---- lengths: 16 threads per batch ----
    {
        int cb = t >> 4, li = t & 15;
        size_t base = (size_t)(blk * NB + cb) * SS;
        int cnt = 0;
        for (int s = li; s < SS; s += 16) cnt += mask_at(maskp, mode, base + s);
        cnt += __shfl_xor(cnt, 1); cnt += __shfl_xor(cnt, 2);
        cnt += __shfl_xor(cnt, 4); cnt += __shfl_xor(cnt, 8);
        if (li == 0) lenS[cb] = cnt;
    }

    // ---- E^T A-fragments built directly from trans/forbidden (resident whole scan) ----
    // A[m=c][k=8q+jj] of tile (mt_g=2w+ml, kt):  E[32kt+8q+jj][32w+16ml+c]
    bf16x8 afrag[2][4];
    #pragma unroll
    for (int ml = 0; ml < 2; ++ml) {
        int col = 32 * w + 16 * ml + c;
        #pragma unroll
        for (int kt = 0; kt < 4; ++kt) {
            #pragma unroll
            for (int jj = 0; jj < 8; ++jj) {
                size_t idx = (size_t)(32 * kt + 8 * q + jj) * TT + col;
                afrag[ml][kt][jj] = mask_at(forb, mode, idx) ? (__bf16)0.f
                                                             : (__bf16)__expf(trans[idx]);
            }
        }
    }

    // ---- init: u0 = exp(start + em[:,0,:] - M0) ----
    {
        int cb = t >> 4, li = t & 15;
        const float* em0 = em + (size_t)(blk * NB + cb) * SS * TT;
        float a[8]; float mx = -1e30f;
        #pragma unroll
        for (int jj = 0; jj < 8; ++jj) {
            int j = li * 8 + jj;
            a[jj] = startt[j] + em0[j];
            mx = fmaxf(mx, a[jj]);
        }
        mx = fmaxf(mx, __shfl_xor(mx, 1)); mx = fmaxf(mx, __shfl_xor(mx, 2));
        mx = fmaxf(mx, __shfl_xor(mx, 4)); mx = fmaxf(mx, __shfl_xor(mx, 8));
        union { __bf16 h[8]; uint4 v; } pk;
        #pragma unroll
        for (int jj = 0; jj < 8; ++jj) pk.h[jj] = (__bf16)__expf(a[jj] - mx);
        *(uint4*)&uS[cb * ROWP + li * 8] = pk.v;
        if (li == 0) MinitS[cb] = mx;
    }
    __syncthreads();

    double Cd = (double)MinitS[c];
    float pending = 1.0f;
    const int len_c = lenS[c];
    int maxlen = 0;
    #pragma unroll
    for (int i = 0; i < NB; ++i) maxlen = max(maxlen, lenS[i]);

    const float* emC = em + (size_t)(blk * NB + c) * SS * TT;
    const int tag0 = 32 * w + 4 * q;   // this lane's D rows (ml=0)
    const int tag1 = tag0 + 16;        // (ml=1)

    int cur = 0;

    // one scan step; em values for the step already in registers
    auto step = [&](float4 e0, float4 e1, bool ren, int s) {
        const __bf16* ub = &uS[cur * (NB * ROWP) + c * ROWP];
        bf16x8 bf0 = *(const bf16x8*)(ub + 8 * q);
        bf16x8 bf1 = *(const bf16x8*)(ub + 32 + 8 * q);
        bf16x8 bf2 = *(const bf16x8*)(ub + 64 + 8 * q);
        bf16x8 bf3 = *(const bf16x8*)(ub + 96 + 8 * q);
        uint2 old0 = *(const uint2*)(ub + tag0);
        uint2 old1 = *(const uint2*)(ub + tag1);

        // scale factors (overlap the LDS wait)
        float sc00 = __expf(e0.x) * pending, sc01 = __expf(e0.y) * pending;
        float sc02 = __expf(e0.z) * pending, sc03 = __expf(e0.w) * pending;
        float sc10 = __expf(e1.x) * pending, sc11 = __expf(e1.y) * pending;
        float sc12 = __expf(e1.z) * pending, sc13 = __expf(e1.w) * pending;

        // 4 independent 2-chains (halves dependent-MFMA latency vs 2 chains of 4)
        f32x4 aA0 = {0,0,0,0}, aB0 = {0,0,0,0}, aA1 = {0,0,0,0}, aB1 = {0,0,0,0};
        aA0 = __builtin_amdgcn_mfma_f32_16x16x32_bf16(afrag[0][0], bf0, aA0, 0, 0, 0);
        aA1 = __builtin_amdgcn_mfma_f32_16x16x32_bf16(afrag[1][0], bf0, aA1, 0, 0, 0);
        aB0 = __builtin_amdgcn_mfma_f32_16x16x32_bf16(afrag[0][2], bf2, aB0, 0, 0, 0);
        aB1 = __builtin_amdgcn_mfma_f32_16x16x32_bf16(afrag[1][2], bf2, aB1, 0, 0, 0);
        aA0 = __builtin_amdgcn_mfma_f32_16x16x32_bf16(afrag[0][1], bf1, aA0, 0, 0, 0);
        aA1 = __builtin_amdgcn_mfma_f32_16x16x32_bf16(afrag[1][1], bf1, aA1, 0, 0, 0);
        aB0 = __builtin_amdgcn_mfma_f32_16x16x32_bf16(afrag[0][3], bf3, aB0, 0, 0, 0);
        aB1 = __builtin_amdgcn_mfma_f32_16x16x32_bf16(afrag[1][3], bf3, aB1, 0, 0, 0);

        float v00 = (aA0[0] + aB0[0]) * sc00, v01 = (aA0[1] + aB0[1]) * sc01;
        float v02 = (aA0[2] + aB0[2]) * sc02, v03 = (aA0[3] + aB0[3]) * sc03;
        float v10 = (aA1[0] + aB1[0]) * sc10, v11 = (aA1[1] + aB1[1]) * sc11;
        float v12 = (aA1[2] + aB1[2]) * sc12, v13 = (aA1[3] + aB1[3]) * sc13;

        const bool active = (s < len_c);

        {
            union { __bf16 h[4]; uint2 v; } p0, p1;
            p0.h[0] = (__bf16)v00; p0.h[1] = (__bf16)v01;
            p0.h[2] = (__bf16)v02; p0.h[3] = (__bf16)v03;
            p1.h[0] = (__bf16)v10; p1.h[1] = (__bf16)v11;
            p1.h[2] = (__bf16)v12; p1.h[3] = (__bf16)v13;
            if (!active) { p0.v = old0; p1.v = old1; }
            __bf16* un = &uS[(cur ^ 1) * (NB * ROWP) + c * ROWP];
            *(uint2*)(un + tag0) = p0.v;
            *(uint2*)(un + tag1) = p1.v;
        }
        if (ren) {
            float m = fmaxf(fmaxf(fmaxf(v00, v01), fmaxf(v02, v03)),
                            fmaxf(fmaxf(v10, v11), fmaxf(v12, v13)));
            m = fmaxf(m, __shfl_xor(m, 16));
            m = fmaxf(m, __shfl_xor(m, 32));
            if (q == 0) wred[c][w] = m;
        }
        wg_barrier_lds();          // LDS-only barrier: em prefetch stays in flight
        if (ren) {
            float4 wm = *(const float4*)wred[c];
            float M = fmaxf(fmaxf(wm.x, wm.y), fmaxf(wm.z, wm.w));
            if (active) { pending = 1.0f / M; Cd += (double)__logf(M); }
        } else if (active) {
            pending = 1.0f;
        }
        cur ^= 1;
    };

    // ---- main scan: groups of GRP steps, em prefetched a full group ahead ----
    int k = 1;
    float4 emc0[GRP], emc1[GRP];
    #pragma unroll
    for (int g = 0; g < GRP; ++g) {
        int kk = k + g; kk = kk < SS ? kk : SS - 1;
        emc0[g] = *(const float4*)(emC + (size_t)kk * TT + tag0);
        emc1[g] = *(const float4*)(emC + (size_t)kk * TT + tag1);
    }

    while (k + GRP <= maxlen) {
        float4 emn0[GRP], emn1[GRP];
        #pragma unroll
        for (int g = 0; g < GRP; ++g) {
            int kk = k + GRP + g; kk = kk < SS ? kk : SS - 1;
            emn0[g] = *(const float4*)(emC + (size_t)kk * TT + tag0);
            emn1[g] = *(const float4*)(emC + (size_t)kk * TT + tag1);
        }
        #pragma unroll
        for (int g = 0; g < GRP; ++g)
            step(emc0[g], emc1[g], g == GRP - 1, k + g);
        #pragma unroll
        for (int g = 0; g < GRP; ++g) { emc0[g] = emn0[g]; emc1[g] = emn1[g]; }
        k += GRP;
    }

    // ---- tail steps (<GRP), renorm every step ----
    while (k < maxlen) {
        float4 e0 = *(const float4*)(emC + (size_t)k * TT + tag0);
        float4 e1 = *(const float4*)(emC + (size_t)k * TT + tag1);
        step(e0, e1, true, k);
        ++k;
    }

    // ---- z = Cd + log(pending * sum_j u_j * exp(end_j)) ----
    __syncthreads();   // full barrier before epilogue (drains everything, once)
    {
        const __bf16* ub = &uS[cur * (NB * ROWP) + c * ROWP];
        float r = 0.f;
        #pragma unroll
        for (int rr = 0; rr < 4; ++rr) r += (float)ub[tag0 + rr] * __expf(endt[tag0 + rr]);
        #pragma unroll
        for (int rr = 0; rr < 4; ++rr) r += (float)ub[tag1 + rr] * __expf(endt[tag1 + rr]);
        r += __shfl_xor(r, 16);
        r += __shfl_xor(r, 32);
        if (q == 0) wred[c][w] = r;
    }
    __syncthreads();
    if (t < NB) {
        float4 wm = *(const float4*)wred[t];
        float tot = (wm.x + wm.y) + (wm.z + wm.w);
        zout[blk * NB + t] = Cd + (double)__logf(pending * tot);
    }
    __syncthreads();

    // ---- posterior path score: 16 threads per batch ----
    {
        int cb = t >> 4, li = t & 15;
        int b = blk * NB + cb;
        int lenb = lenS[cb];
        const int* tg = tags + (size_t)b * SS;
        const float* emb = em + (size_t)b * SS * TT;
        double local = 0.0; int fcnt = 0;
        for (int kk = 1 + li; kk < lenb; kk += 16) {
            int tp = tg[kk - 1], tc = tg[kk];
            if (mask_at(forb, mode, (size_t)tp * TT + tc)) fcnt++;
            else local += (double)trans[tp * TT + tc];
            local += (double)emb[(size_t)kk * TT + tc];
        }
        if (li == 0) {
            local += (double)startt[tg[0]] + (double)emb[tg[0]];
            local += (double)endt[tg[lenb - 1]];
        }
        local += __shfl_xor(local, 1); local += __shfl_xor(local, 2);
        local += __shfl_xor(local, 4); local += __shfl_xor(local, 8);
        fcnt += __shfl_xor(fcnt, 1); fcnt += __shfl_xor(fcnt, 2);
        fcnt += __shfl_xor(fcnt, 4); fcnt += __shfl_xor(fcnt, 8);
        if (li == 0) postout[b] = local - 100000.0 * (double)fcnt;
    }
}

// ---- nll = mean(post) - mean(z) ----
__global__ void fin_kernel(const double* __restrict__ z, const double* __restrict__ post,
                           float* __restrict__ out) {
    int t = threadIdx.x; // 64 threads, 1 wave
    double pv = post[t];
    double zv = z[t];
    #pragma unroll
    for (int off = 32; off >= 1; off >>= 1) {
        pv += __shfl_xor(pv, off);
        zv += __shfl_xor(zv, off);
    }
    if (t == 0) out[0] = (float)((pv - zv) / (double)BB);
}

extern "C" void kernel_launch(void* const* d_in, const int* in_sizes, int n_in,
                              void* d_out, int out_size, void* d_ws, size_t ws_size,
                              hipStream_t stream) {
    const float* em     = (const float*)d_in[0];
    const void*  maskp  = d_in[1];
    const int*   tags   = (const int*)d_in[2];
    const void*  forb   = d_in[3];
    const float* trans  = (const float*)d_in[4];
    const float* startt = (const float*)d_in[5];
    const float* endt   = (const float*)d_in[6];

    double* z    = (double*)d_ws;            // 64 doubles
    double* post = z + BB;                   // 64 doubles

    fwd_kernel<<<FWD_BLOCKS, 256, 0, stream>>>(em, maskp, tags, forb, trans, startt, endt, z, post);
    fin_kernel<<<1, 64, 0, stream>>>(z, post, (float*)d_out);
}

// Round 6
// 810.697 us; speedup vs baseline: 1.5240x; 1.5240x over previous
//
#include <hip/hip_runtime.h>
#include <hip/hip_bf16.h>
#include <stdint.h>

#define BB 64
#define SS 2048
#define TT 128
#define GRP 6              // renorm interval AND em prefetch group (6*10.8 < 88.7 e-folds)

typedef __bf16 bf16x8 __attribute__((ext_vector_type(8)));
typedef float  f32x4  __attribute__((ext_vector_type(4)));

// Raw workgroup barrier that does NOT drain vmcnt (LDS ordering only):
// keeps the grouped em prefetch in flight across the per-step barrier.
__device__ __forceinline__ void wg_barrier_lds() {
    asm volatile("" ::: "memory");
    __builtin_amdgcn_s_waitcnt(0xc07f);   // lgkmcnt(0), vmcnt/expcnt no-wait
    __builtin_amdgcn_s_barrier();
    asm volatile("" ::: "memory");
}

// ---- bool-layout detection: mask[0,0] is always true (len >= 1024) ----
__device__ __forceinline__ int detect_mode(const void* maskp) {
    uint32_t w0 = ((const uint32_t*)maskp)[0];
    if (w0 == 1u) return 0;
    if (w0 == 0x3F800000u) return 2;
    if (w0 == 0x3F803F80u) return 3;
    return 1;
}
__device__ __forceinline__ int mask_at(const void* maskp, int mode, size_t idx) {
    if (mode == 0) return ((const int*)maskp)[idx] != 0;
    if (mode == 1) return ((const unsigned char*)maskp)[idx] != 0;
    if (mode == 2) return ((const float*)maskp)[idx] != 0.f;
    return ((const unsigned short*)maskp)[idx] != 0;
}

// ---- MFMA forward scan + posterior, ONE batch per block (64 blocks) ----
// Per-CU em stream = 512 B/step -> far under the single-CU miss-throughput cap.
__global__ __launch_bounds__(256, 1) void fwd_kernel(
    const float* __restrict__ em, const void* __restrict__ maskp,
    const int* __restrict__ tags, const void* __restrict__ forb,
    const float* __restrict__ trans,
    const float* __restrict__ startt, const float* __restrict__ endt,
    double* __restrict__ zout, double* __restrict__ postout)
{
    const int t = threadIdx.x;
    const int w = t >> 6;          // wave 0..3 (owns t_out rows 32w..32w+31)
    const int lane = t & 63;
    const int q = lane >> 4;       // quad 0..3
    const int c = lane & 15;       // MFMA n-column (all columns replicate batch b)
    const int b = blockIdx.x;      // the batch

    __shared__ __bf16 uS[2][TT];               // double-buffered u (bf16), one row
    __shared__ __align__(16) float wred[4];    // per-wave reduction slots
    __shared__ int   redi[4];
    __shared__ double redd[4];
    __shared__ int   redc[4];
    __shared__ float Minit;

    const int mode = detect_mode(maskp);

    // ---- length of this batch (contiguous mask prefix) ----
    {
        int cnt = 0;
        for (int s = t; s < SS; s += 256) cnt += mask_at(maskp, mode, (size_t)b * SS + s);
        #pragma unroll
        for (int off = 32; off >= 1; off >>= 1) cnt += __shfl_xor(cnt, off);
        if (lane == 0) redi[w] = cnt;
    }
    __syncthreads();
    const int len = redi[0] + redi[1] + redi[2] + redi[3];

    // ---- E^T A-fragments from trans/forbidden (register-resident whole scan) ----
    // A[m=c][k=8q+jj] of tile (mt_g=2w+ml, kt):  E[32kt+8q+jj][32w+16ml+c]
    bf16x8 afrag[2][4];
    #pragma unroll
    for (int ml = 0; ml < 2; ++ml) {
        int col = 32 * w + 16 * ml + c;
        #pragma unroll
        for (int kt = 0; kt < 4; ++kt) {
            #pragma unroll
            for (int jj = 0; jj < 8; ++jj) {
                size_t idx = (size_t)(32 * kt + 8 * q + jj) * TT + col;
                afrag[ml][kt][jj] = mask_at(forb, mode, idx) ? (__bf16)0.f
                                                             : (__bf16)__expf(trans[idx]);
            }
        }
    }

    const float* emB = em + (size_t)b * SS * TT;

    // ---- init: u0 = exp(start + em[:,0,:] - M0), threads 0..15 ----
    if (t < 16) {
        float a[8]; float mx = -1e30f;
        #pragma unroll
        for (int jj = 0; jj < 8; ++jj) {
            int j = t * 8 + jj;
            a[jj] = startt[j] + emB[j];
            mx = fmaxf(mx, a[jj]);
        }
        mx = fmaxf(mx, __shfl_xor(mx, 1)); mx = fmaxf(mx, __shfl_xor(mx, 2));
        mx = fmaxf(mx, __shfl_xor(mx, 4)); mx = fmaxf(mx, __shfl_xor(mx, 8));
        union { __bf16 h[8]; uint4 v; } pk;
        #pragma unroll
        for (int jj = 0; jj < 8; ++jj) pk.h[jj] = (__bf16)__expf(a[jj] - mx);
        *(uint4*)&uS[0][t * 8] = pk.v;
        if (t == 0) Minit = mx;
    }
    __syncthreads();

    double Cd = (double)Minit;
    float pending = 1.0f;

    const int tag0 = 32 * w + 4 * q;   // this lane's D rows (ml=0)
    const int tag1 = tag0 + 16;        // (ml=1)

    int cur = 0;

    // one scan step; em values for the step already in registers
    auto step = [&](float4 e0, float4 e1, bool ren) {
        const __bf16* ub = &uS[cur][0];
        bf16x8 bf0 = *(const bf16x8*)(ub + 8 * q);        // same addr across c: broadcast
        bf16x8 bf1 = *(const bf16x8*)(ub + 32 + 8 * q);
        bf16x8 bf2 = *(const bf16x8*)(ub + 64 + 8 * q);
        bf16x8 bf3 = *(const bf16x8*)(ub + 96 + 8 * q);

        // scale factors (overlap the LDS wait)
        float sc00 = __expf(e0.x) * pending, sc01 = __expf(e0.y) * pending;
        float sc02 = __expf(e0.z) * pending, sc03 = __expf(e0.w) * pending;
        float sc10 = __expf(e1.x) * pending, sc11 = __expf(e1.y) * pending;
        float sc12 = __expf(e1.z) * pending, sc13 = __expf(e1.w) * pending;

        // 4 independent 2-chains
        f32x4 aA0 = {0,0,0,0}, aB0 = {0,0,0,0}, aA1 = {0,0,0,0}, aB1 = {0,0,0,0};
        aA0 = __builtin_amdgcn_mfma_f32_16x16x32_bf16(afrag[0][0], bf0, aA0, 0, 0, 0);
        aA1 = __builtin_amdgcn_mfma_f32_16x16x32_bf16(afrag[1][0], bf0, aA1, 0, 0, 0);
        aB0 = __builtin_amdgcn_mfma_f32_16x16x32_bf16(afrag[0][2], bf2, aB0, 0, 0, 0);
        aB1 = __builtin_amdgcn_mfma_f32_16x16x32_bf16(afrag[1][2], bf2, aB1, 0, 0, 0);
        aA0 = __builtin_amdgcn_mfma_f32_16x16x32_bf16(afrag[0][1], bf1, aA0, 0, 0, 0);
        aA1 = __builtin_amdgcn_mfma_f32_16x16x32_bf16(afrag[1][1], bf1, aA1, 0, 0, 0);
        aB0 = __builtin_amdgcn_mfma_f32_16x16x32_bf16(afrag[0][3], bf3, aB0, 0, 0, 0);
        aB1 = __builtin_amdgcn_mfma_f32_16x16x32_bf16(afrag[1][3], bf3, aB1, 0, 0, 0);

        float v00 = (aA0[0] + aB0[0]) * sc00, v01 = (aA0[1] + aB0[1]) * sc01;
        float v02 = (aA0[2] + aB0[2]) * sc02, v03 = (aA0[3] + aB0[3]) * sc03;
        float v10 = (aA1[0] + aB1[0]) * sc10, v11 = (aA1[1] + aB1[1]) * sc11;
        float v12 = (aA1[2] + aB1[2]) * sc12, v13 = (aA1[3] + aB1[3]) * sc13;

        // write new u (c==0 lanes only; all c columns hold identical values)
        if (c == 0) {
            union { __bf16 h[4]; uint2 v; } p0, p1;
            p0.h[0] = (__bf16)v00; p0.h[1] = (__bf16)v01;
            p0.h[2] = (__bf16)v02; p0.h[3] = (__bf16)v03;
            p1.h[0] = (__bf16)v10; p1.h[1] = (__bf16)v11;
            p1.h[2] = (__bf16)v12; p1.h[3] = (__bf16)v13;
            __bf16* un = &uS[cur ^ 1][0];
            *(uint2*)(un + tag0) = p0.v;
            *(uint2*)(un + tag1) = p1.v;
        }
        if (ren) {
            float m = fmaxf(fmaxf(fmaxf(v00, v01), fmaxf(v02, v03)),
                            fmaxf(fmaxf(v10, v11), fmaxf(v12, v13)));
            m = fmaxf(m, __shfl_xor(m, 16));
            m = fmaxf(m, __shfl_xor(m, 32));
            if (lane == 0) wred[w] = m;
        }
        wg_barrier_lds();          // LDS-only barrier: em prefetch stays in flight
        if (ren) {
            float4 wm = *(const float4*)wred;
            float M = fmaxf(fmaxf(wm.x, wm.y), fmaxf(wm.z, wm.w));
            pending = 1.0f / M;
            Cd += (double)__logf(M);
        } else {
            pending = 1.0f;
        }
        cur ^= 1;
    };

    // ---- main scan: groups of GRP steps, em prefetched a full group ahead ----
    int k = 1;
    float4 emc0[GRP], emc1[GRP];
    #pragma unroll
    for (int g = 0; g < GRP; ++g) {
        int kk = k + g; kk = kk < SS ? kk : SS - 1;
        emc0[g] = *(const float4*)(emB + (size_t)kk * TT + tag0);
        emc1[g] = *(const float4*)(emB + (size_t)kk * TT + tag1);
    }

    while (k + GRP <= len) {
        float4 emn0[GRP], emn1[GRP];
        #pragma unroll
        for (int g = 0; g < GRP; ++g) {
            int kk = k + GRP + g; kk = kk < SS ? kk : SS - 1;
            emn0[g] = *(const float4*)(emB + (size_t)kk * TT + tag0);
            emn1[g] = *(const float4*)(emB + (size_t)kk * TT + tag1);
        }
        #pragma unroll
        for (int g = 0; g < GRP; ++g)
            step(emc0[g], emc1[g], g == GRP - 1);
        #pragma unroll
        for (int g = 0; g < GRP; ++g) { emc0[g] = emn0[g]; emc1[g] = emn1[g]; }
        k += GRP;
    }

    // ---- tail steps (<GRP), renorm every step ----
    while (k < len) {
        float4 e0 = *(const float4*)(emB + (size_t)k * TT + tag0);
        float4 e1 = *(const float4*)(emB + (size_t)k * TT + tag1);
        step(e0, e1, true);
        ++k;
    }

    // ---- z = Cd + log(pending * sum_j u_j * exp(end_j)) ----
    __syncthreads();   // full drain once before epilogue
    {
        const __bf16* ub = &uS[cur][0];
        float r = 0.f;
        #pragma unroll
        for (int rr = 0; rr < 4; ++rr) r += (float)ub[tag0 + rr] * __expf(endt[tag0 + rr]);
        #pragma unroll
        for (int rr = 0; rr < 4; ++rr) r += (float)ub[tag1 + rr] * __expf(endt[tag1 + rr]);
        r += __shfl_xor(r, 16);
        r += __shfl_xor(r, 32);
        if (lane == 0) wred[w] = r;
    }
    __syncthreads();
    if (t == 0) {
        float tot = (wred[0] + wred[1]) + (wred[2] + wred[3]);
        zout[b] = Cd + (double)__logf(pending * tot);
    }
    __syncthreads();

    // ---- posterior path score for this batch (256 threads strided) ----
    {
        const int* tg = tags + (size_t)b * SS;
        double local = 0.0; int fcnt = 0;
        for (int kk = 1 + t; kk < len; kk += 256) {
            int tp = tg[kk - 1], tc = tg[kk];
            if (mask_at(forb, mode, (size_t)tp * TT + tc)) fcnt++;
            else local += (double)trans[tp * TT + tc];
            local += (double)emB[(size_t)kk * TT + tc];
        }
        if (t == 0) {
            local += (double)startt[tg[0]] + (double)emB[tg[0]];
            local += (double)endt[tg[len - 1]];
        }
        #pragma unroll
        for (int off = 32; off >= 1; off >>= 1) {
            local += __shfl_xor(local, off);
            fcnt  += __shfl_xor(fcnt, off);
        }
        if (lane == 0) { redd[w] = local; redc[w] = fcnt; }
        __syncthreads();
        if (t == 0) {
            double tot = redd[0] + redd[1] + redd[2] + redd[3];
            int fc = redc[0] + redc[1] + redc[2] + redc[3];
            postout[b] = tot - 100000.0 * (double)fc;
        }
    }
}

// ---- nll = mean(post) - mean(z) ----
__global__ void fin_kernel(const double* __restrict__ z, const double* __restrict__ post,
                           float* __restrict__ out) {
    int t = threadIdx.x; // 64 threads, 1 wave
    double pv = post[t];
    double zv = z[t];
    #pragma unroll
    for (int off = 32; off >= 1; off >>= 1) {
        pv += __shfl_xor(pv, off);
        zv += __shfl_xor(zv, off);
    }
    if (t == 0) out[0] = (float)((pv - zv) / (double)BB);
}

extern "C" void kernel_launch(void* const* d_in, const int* in_sizes, int n_in,
                              void* d_out, int out_size, void* d_ws, size_t ws_size,
                              hipStream_t stream) {
    const float* em     = (const float*)d_in[0];
    const void*  maskp  = d_in[1];
    const int*   tags   = (const int*)d_in[2];
    const void*  forb   = d_in[3];
    const float* trans  = (const float*)d_in[4];
    const float* startt = (const float*)d_in[5];
    const float* endt   = (const float*)d_in[6];

    double* z    = (double*)d_ws;            // 64 doubles
    double* post = z + BB;                   // 64 doubles

    fwd_kernel<<<BB, 256, 0, stream>>>(em, maskp, tags, forb, trans, startt, endt, z, post);
    fin_kernel<<<1, 64, 0, stream>>>(z, post, (float*)d_out);
}